// Round 13
// baseline (756.342 us; speedup 1.0000x reference)
//
#include <hip/hip_runtime.h>
#include <cstdint>
#include <cstddef>

// SpiralAutoencoder forward, MI355X gfx950.
// Inputs f32, indices i32, output f32. Internal activations bf16, fp32 accum.
// Spiral convs = MFMA bf16 GEMM, software-pipelined K-loop (R9).
// LSTM v4 (REVERTED per R11/R12 postmortems: v5/v5b regressed; v4=63us is the
//   measured optimum: xproj via MFMA, recurrence 1 barrier/step, h bf16 LDS).
// Encoder convs fuse their input pool (on-the-fly gather in pipelined A-fetch).
// Decoder pools separate (TLP hides gather latency), 8 ch/thread 16B loads.

typedef unsigned short u16;
typedef __attribute__((ext_vector_type(8))) short short8;
typedef __attribute__((ext_vector_type(4))) float float4v;
#define CDIV(a,b) (((a)+(b)-1)/(b))
#define POOL_CAP 64

__device__ __forceinline__ float bf(u16 u){ return __uint_as_float(((unsigned)u)<<16); }
__device__ __forceinline__ u16 fb(float x){
  unsigned u = __float_as_uint(x);
  unsigned r = u + 0x7fffu + ((u>>16)&1u);   // RNE
  return (u16)(r>>16);
}
__device__ __forceinline__ float lo16(unsigned u){ return __uint_as_float(u<<16); }
__device__ __forceinline__ float hi16(unsigned u){ return __uint_as_float(u & 0xffff0000u); }

struct WCast { const float* src[7]; int cum[8]; };
struct Lists {
  const int* rows[8];
  int nnz[8];
  int curoff[8];
  int lstoff[8];
};

// ---- fused setup: fill lists | cast weights | audio emb | conv3 ----
__global__ void __launch_bounds__(256) setup_k(
    Lists L, int totN, int NF, int* __restrict__ curBase, int* __restrict__ lstBase,
    WCast C, int totW, int NC, u16* __restrict__ Wbf,
    const float* __restrict__ audio, const float* __restrict__ audW,
    const float* __restrict__ audB, float* __restrict__ h0,
    const float* __restrict__ actor, const int* __restrict__ sp0,
    const float* __restrict__ encW0, const float* __restrict__ encB0,
    u16* __restrict__ outA){
  int blk = blockIdx.x;
  int tid = threadIdx.x;
  if (blk < NF){
    int i = blk*256 + tid;
    if (i < totN){
      int off = i, k = 0;
      while (off >= L.nnz[k]){ off -= L.nnz[k]; k++; }
      int r = L.rows[k][off];
      int p = atomicAdd(curBase + L.curoff[k] + r, 1);
      if (p < POOL_CAP) lstBase[L.lstoff[k] + r*POOL_CAP + p] = off;
    }
    return;
  }
  blk -= NF;
  if (blk < NC){
    int i = blk*256 + tid;
    if (i < totW){
      int k = 0;
      while (i >= C.cum[k+1]) k++;
      Wbf[i] = fb(C.src[k][i - C.cum[k]]);
    }
    return;
  }
  blk -= NC;
  if (blk < 32){
    int t = blk;
    int f = tid >> 2, sl = tid & 3;
    const float4* x4 = (const float4*)(audio + t*1536);
    const float4* w4 = (const float4*)(audW + f*1536);
    float acc = 0.f;
    for (int k=sl; k<384; k+=4){
      float4 xv = x4[k], wv = w4[k];
      acc += xv.x*wv.x + xv.y*wv.y + xv.z*wv.z + xv.w*wv.w;
    }
    acc += __shfl_down(acc, 2, 64);
    acc += __shfl_down(acc, 1, 64);
    if (sl == 0) h0[t*128 + f] = acc + audB[f];
    return;
  }
  blk -= 32;
  int i = blk*256 + tid;                     // conv3: IC=3 spiral conv
  if (i >= 5023*32) return;
  int o = i % 32; int v = i / 32;
  const float* wrow = encW0 + (size_t)o*27;
  const int* vix = sp0 + v*9;
  float acc = encB0[o];
  for (int s=0;s<9;s++){
    const float* xr = actor + (size_t)vix[s]*3;
    acc += xr[0]*wrow[s*3] + xr[1]*wrow[s*3+1] + xr[2]*wrow[s*3+2];
  }
  if (acc < 0.f) acc = expm1f(acc);
  outA[i] = fb(acc);
}

// ---- MFMA spiral conv, software-pipelined (R9), decoder path ----
template<int IC, int BN, int BM>
__global__ void __launch_bounds__(256) conv_mfma(
    const u16* __restrict__ x, const int* __restrict__ idx,
    const u16* __restrict__ Wb, const float* __restrict__ bias,
    u16* __restrict__ out, int V, int OC, int M){
  constexpr int K = 9*IC;
  constexpr int KC = K/32;
  constexpr int NT = BN/16;
  constexpr int MT = BM/64;
  constexpr int LOG2 = (IC==32?5: IC==64?6: IC==128?7:8);
  constexpr int AST = 40;
  __shared__ u16 Asm[2][BM*AST];
  __shared__ u16 Bsm[2][BN*AST];
  __shared__ int rowB[BM], rowV[BM];
  __shared__ int sidx[BM*9];
  int t = threadIdx.x;
  int m0 = blockIdx.x*BM;
  int o0 = blockIdx.y*BN;
  if (t < BM){
    int mg = m0 + t;
    if (mg < M){ int b = mg / V; rowB[t] = b; rowV[t] = mg - b*V; }
    else rowB[t] = -1;
  }
  __syncthreads();
  for (int i=t; i<BM*9; i+=256){
    int r = i/9, s = i - r*9;
    sidx[i] = (rowB[r] >= 0) ? idx[rowV[r]*9 + s] : 0;
  }
  int lane = t & 63, wave = t >> 6;
  int quad = lane >> 4, col = lane & 15;
  float4v acc[MT][NT];
  #pragma unroll
  for (int mi=0;mi<MT;mi++)
    #pragma unroll
    for (int nt=0;nt<NT;nt++) acc[mi][nt] = (float4v)0.f;

  uint4 aval[MT]; uint4 bval;
  auto fetch = [&](int kc){
    int s  = (kc*32) >> LOG2;
    int c0 = (kc*32) & (IC-1);
    #pragma unroll
    for (int rpt=0; rpt<MT; ++rpt){
      int seg = t + 256*rpt;
      int arow = seg >> 2, aq = seg & 3;
      int b = rowB[arow];
      uint4 v = {0u,0u,0u,0u};
      if (b >= 0){
        int ix = sidx[arow*9 + s];
        v = *(const uint4*)(x + ((size_t)b*V + ix)*IC + c0 + aq*8);
      }
      aval[rpt] = v;
    }
    if (t < BN*4){
      int br = t >> 2, bq = t & 3;
      bval = *(const uint4*)(Wb + (size_t)(o0+br)*K + kc*32 + bq*8);
    }
  };

  __syncthreads();
  fetch(0);

  for (int kc = 0; kc < KC; ++kc){
    int buf = kc & 1;
    #pragma unroll
    for (int rpt=0; rpt<MT; ++rpt){
      int seg = t + 256*rpt;
      int arow = seg >> 2, aq = seg & 3;
      *(uint4*)&Asm[buf][arow*AST + aq*8] = aval[rpt];
    }
    if (t < BN*4){
      int br = t >> 2, bq = t & 3;
      *(uint4*)&Bsm[buf][br*AST + bq*8] = bval;
    }
    __syncthreads();
    if (kc+1 < KC) fetch(kc+1);
    short8 a[MT];
    #pragma unroll
    for (int mi=0;mi<MT;mi++)
      a[mi] = *(const short8*)&Asm[buf][(wave*MT*16 + mi*16 + col)*AST + quad*8];
    #pragma unroll
    for (int nt=0; nt<NT; ++nt){
      short8 bfr = *(const short8*)&Bsm[buf][(nt*16 + col)*AST + quad*8];
      #pragma unroll
      for (int mi=0;mi<MT;mi++)
        acc[mi][nt] = __builtin_amdgcn_mfma_f32_16x16x32_bf16(a[mi], bfr, acc[mi][nt], 0, 0, 0);
    }
  }
  #pragma unroll
  for (int mi=0;mi<MT;mi++){
    #pragma unroll
    for (int nt=0; nt<NT; ++nt){
      int o = o0 + nt*16 + col;
      float bv = bias[o];
      #pragma unroll
      for (int r=0;r<4;r++){
        int mg = m0 + wave*MT*16 + mi*16 + quad*4 + r;
        if (mg < M){
          float val = acc[mi][nt][r] + bv;
          if (val < 0.f) val = expm1f(val);
          out[(size_t)mg*OC + o] = fb(val);
        }
      }
    }
  }
}

// ---- encoder conv with FUSED input pool (B=1, BM=64):
//      A-row = pooled[idx[v,s]], pooled[r,c] = sum_e vals[e]*xprev[cols[e],c] ----
template<int IC, int BN>
__global__ void __launch_bounds__(256) conv_pool_mfma(
    const u16* __restrict__ xprev, const int* __restrict__ idx,
    const int* __restrict__ cols, const float* __restrict__ vals,
    const int* __restrict__ cur, const int* __restrict__ lst,
    const u16* __restrict__ Wb, const float* __restrict__ bias,
    u16* __restrict__ out, int V, int OC, int M){
  constexpr int K = 9*IC;
  constexpr int KC = K/32;
  constexpr int NT = BN/16;
  constexpr int LOG2 = (IC==32?5: IC==64?6: IC==128?7:8);
  constexpr int AST = 40;
  __shared__ u16 Asm[2][64*AST];
  __shared__ u16 Bsm[2][BN*AST];
  __shared__ int sidx[64*9];
  int t = threadIdx.x;
  int m0 = blockIdx.x*64;
  int o0 = blockIdx.y*BN;
  for (int i=t; i<64*9; i+=256){
    int r = i/9, s = i - r*9;
    sidx[i] = (m0 + r < M) ? idx[(m0+r)*9 + s] : -1;
  }
  int lane = t & 63, wave = t >> 6;
  int quad = lane >> 4, col = lane & 15;
  float4v acc[NT];
  #pragma unroll
  for (int nt=0;nt<NT;nt++) acc[nt] = (float4v)0.f;

  uint4 aval; uint4 bval;
  int arow = t >> 2, aq = t & 3;
  auto fetch = [&](int kc){
    int s  = (kc*32) >> LOG2;
    int c0 = (kc*32) & (IC-1);
    int r = sidx[arow*9 + s];
    float p0=0,p1=0,p2=0,p3=0,p4=0,p5=0,p6=0,p7=0;
    if (r >= 0){
      int deg = cur[r]; if (deg > POOL_CAP) deg = POOL_CAP;
      const int* le = lst + r*POOL_CAP;
      for (int e=0;e<deg;e++){
        int ee = le[e];
        float v = vals[ee];
        uint4 xv = *(const uint4*)(xprev + (size_t)cols[ee]*IC + c0 + aq*8);
        p0 = fmaf(v, lo16(xv.x), p0); p1 = fmaf(v, hi16(xv.x), p1);
        p2 = fmaf(v, lo16(xv.y), p2); p3 = fmaf(v, hi16(xv.y), p3);
        p4 = fmaf(v, lo16(xv.z), p4); p5 = fmaf(v, hi16(xv.z), p5);
        p6 = fmaf(v, lo16(xv.w), p6); p7 = fmaf(v, hi16(xv.w), p7);
      }
    }
    aval.x = ((unsigned)fb(p0)) | (((unsigned)fb(p1))<<16);
    aval.y = ((unsigned)fb(p2)) | (((unsigned)fb(p3))<<16);
    aval.z = ((unsigned)fb(p4)) | (((unsigned)fb(p5))<<16);
    aval.w = ((unsigned)fb(p6)) | (((unsigned)fb(p7))<<16);
    if (t < BN*4){
      int br = t >> 2, bq = t & 3;
      bval = *(const uint4*)(Wb + (size_t)(o0+br)*K + kc*32 + bq*8);
    }
  };

  __syncthreads();
  fetch(0);

  for (int kc = 0; kc < KC; ++kc){
    int buf = kc & 1;
    *(uint4*)&Asm[buf][arow*AST + aq*8] = aval;
    if (t < BN*4){
      int br = t >> 2, bq = t & 3;
      *(uint4*)&Bsm[buf][br*AST + bq*8] = bval;
    }
    __syncthreads();
    if (kc+1 < KC) fetch(kc+1);
    short8 a = *(const short8*)&Asm[buf][(wave*16 + col)*AST + quad*8];
    #pragma unroll
    for (int nt=0; nt<NT; ++nt){
      short8 bfr = *(const short8*)&Bsm[buf][(nt*16 + col)*AST + quad*8];
      acc[nt] = __builtin_amdgcn_mfma_f32_16x16x32_bf16(a, bfr, acc[nt], 0, 0, 0);
    }
  }
  #pragma unroll
  for (int nt=0; nt<NT; ++nt){
    int o = o0 + nt*16 + col;
    float bv = bias[o];
    #pragma unroll
    for (int r=0;r<4;r++){
      int mg = m0 + wave*16 + quad*4 + r;
      if (mg < M){
        float val = acc[nt][r] + bv;
        if (val < 0.f) val = expm1f(val);
        out[(size_t)mg*OC + o] = fb(val);
      }
    }
  }
}

// ---- pool gather, 8 channels/thread (16B loads), decoder path ----
__global__ void pool_g8_k(const u16* __restrict__ x, const int* __restrict__ cols,
                          const float* __restrict__ vals, const int* __restrict__ cur,
                          const int* __restrict__ lst, u16* __restrict__ out,
                          int B, int Vin, int Vout, int C){
  int C8 = C >> 3;
  int total = B*Vout*C8;
  int i = blockIdx.x*blockDim.x + threadIdx.x;
  if (i >= total) return;
  int c8 = i % C8; int tt = i / C8; int r = tt % Vout; int b = tt / Vout;
  int deg = cur[r]; if (deg > POOL_CAP) deg = POOL_CAP;
  const int* le = lst + r*POOL_CAP;
  float a0=0.f,a1=0.f,a2=0.f,a3=0.f,a4=0.f,a5=0.f,a6=0.f,a7=0.f;
  for (int k=0;k<deg;k++){
    int e = le[k];
    float v = vals[e];
    uint4 xv = *(const uint4*)(x + ((size_t)b*Vin + (size_t)cols[e])*C + c8*8);
    a0 += v*lo16(xv.x); a1 += v*hi16(xv.x);
    a2 += v*lo16(xv.y); a3 += v*hi16(xv.y);
    a4 += v*lo16(xv.z); a5 += v*hi16(xv.z);
    a6 += v*lo16(xv.w); a7 += v*hi16(xv.w);
  }
  uint4 o;
  o.x = ((unsigned)fb(a0)) | (((unsigned)fb(a1))<<16);
  o.y = ((unsigned)fb(a2)) | (((unsigned)fb(a3))<<16);
  o.z = ((unsigned)fb(a4)) | (((unsigned)fb(a5))<<16);
  o.w = ((unsigned)fb(a6)) | (((unsigned)fb(a7))<<16);
  *(uint4*)(out + ((size_t)b*Vout + (size_t)r)*C + c8*8) = o;
}

// ---- encoder linear, split-K + broadcast into h0[:,64:] ----
__global__ void __launch_bounds__(256) enc_lin_k(
    const u16* __restrict__ x, const float* __restrict__ W,
    const float* __restrict__ b, float* __restrict__ h0){
  int f = blockIdx.x;
  int t = threadIdx.x;
  const ushort4* x4 = (const ushort4*)x;
  const float4* w4 = (const float4*)(W + (size_t)f*5120);
  float acc = 0.f;
  for (int k=t; k<1280; k+=256){
    ushort4 xv = x4[k]; float4 wv = w4[k];
    acc += bf(xv.x)*wv.x + bf(xv.y)*wv.y + bf(xv.z)*wv.z + bf(xv.w)*wv.w;
  }
  #pragma unroll
  for (int off=32; off; off>>=1) acc += __shfl_down(acc, off, 64);
  __shared__ float red[4];
  if ((t & 63) == 0) red[t>>6] = acc;
  __syncthreads();
  if (t < 32){
    float zf = b[f] + red[0] + red[1] + red[2] + red[3];
    h0[t*128 + 64 + f] = zf;
  }
}

// ---- LSTM v4 (reverted: measured optimum 63us) ----
__device__ __forceinline__ float sigm(float x){ return 1.f/(1.f+__expf(-x)); }
__device__ __forceinline__ float tanhfast(float x){ return 1.f - 2.f/(__expf(2.f*x)+1.f); }

__global__ void __launch_bounds__(256) lstm3_k(
    const float* __restrict__ h0,
    const float* __restrict__ l0_Wih, const float* __restrict__ l0_Whh,
    const float* __restrict__ l0_bih, const float* __restrict__ l0_bhh,
    const float* __restrict__ l12_Wih, const float* __restrict__ l12_Whh,
    const float* __restrict__ l12_bih, const float* __restrict__ l12_bhh,
    float* __restrict__ latent){
  __shared__ __align__(16) u16 xb[32*136];       // x, bf16, stride 136
  __shared__ __align__(16) float xp[2*32*128];   // xproj+bias, [dir][t][j]
  __shared__ __align__(16) u16 obuf[32*64];
  __shared__ __align__(16) u16 hsh[2][32];
  __shared__ float bias_l[256];
  int t = threadIdx.x;
  int lane = t & 63, wave = t >> 6;
  int quad = lane >> 4, col = lane & 15;
  int dir = t >> 7;                 // recurrence: waves 0,1 -> dir0; 2,3 -> dir1
  bool rev = (dir == 1);
  int w2 = (t >> 6) & 1;            // which wave within dir
  int unit = w2*16 + col;           // hidden unit 0..31
  int jj = quad*32 + unit;          // Wih/Whh row (gate*32+unit)

  for (int i=t;i<32*128;i+=256){ int tt=i>>7, k=i&127; xb[tt*136+k]=fb(h0[i]); }

  for (int layer=0; layer<3; layer++){
    int IN = (layer==0)?128:64;
    const float *Wih,*Whh,*bih,*bhh;
    if (layer==0){ Wih=l0_Wih; Whh=l0_Whh; bih=l0_bih; bhh=l0_bhh; }
    else {
      int mb=(layer-1)*2;
      Wih=l12_Wih + (size_t)mb*128*64; Whh=l12_Whh + (size_t)mb*128*32;
      bih=l12_bih + mb*128; bhh=l12_bhh + mb*128;
    }
    // per-thread recurrence weights (row jj of this dir's Whh), packed bf16
    const float* WhhD = Whh + (size_t)dir*128*32 + (size_t)jj*32;
    unsigned whh[16];
    #pragma unroll
    for (int k=0;k<16;k++){
      float2 w = *(const float2*)&WhhD[2*k];
      whh[k] = ((unsigned)fb(w.x)) | (((unsigned)fb(w.y))<<16);
    }
    bias_l[t] = bih[dir*128 + (t&127)] + bhh[dir*128 + (t&127)];
    if (quad == 0) hsh[dir][unit] = 0;
    float creg = 0.f;                // c for this lane's unit (quad==0 lanes)
    __syncthreads();

    // ---- Phase A: xproj[dirA][t][j] = x @ WihA^T + bias, via MFMA ----
    {
      int dirA = wave >> 1, o0 = (wave & 1)*64;
      const float* WA = Wih + (size_t)dirA*128*IN;
      float4v acc[2][4];
      #pragma unroll
      for (int mi=0;mi<2;mi++)
        #pragma unroll
        for (int nt=0;nt<4;nt++) acc[mi][nt] = (float4v)0.f;
      for (int kc=0; kc<IN/32; ++kc){
        short8 bfrag[4];
        #pragma unroll
        for (int nt=0;nt<4;nt++){
          const float* src = WA + (size_t)(o0+nt*16+col)*IN + kc*32 + quad*8;
          float4 w0 = *(const float4*)src;
          float4 w1 = *(const float4*)(src+4);
          alignas(16) u16 tmp[8] = {fb(w0.x),fb(w0.y),fb(w0.z),fb(w0.w),
                                    fb(w1.x),fb(w1.y),fb(w1.z),fb(w1.w)};
          bfrag[nt] = *(const short8*)tmp;
        }
        short8 afrag[2];
        #pragma unroll
        for (int mi=0;mi<2;mi++)
          afrag[mi] = *(const short8*)&xb[(mi*16+col)*136 + kc*32 + quad*8];
        #pragma unroll
        for (int nt=0;nt<4;nt++)
          #pragma unroll
          for (int mi=0;mi<2;mi++)
            acc[mi][nt] = __builtin_amdgcn_mfma_f32_16x16x32_bf16(afrag[mi], bfrag[nt], acc[mi][nt], 0, 0, 0);
      }
      #pragma unroll
      for (int mi=0;mi<2;mi++)
        #pragma unroll
        for (int nt=0;nt<4;nt++){
          int j = o0 + nt*16 + col;
          float bv = bias_l[dirA*128 + j];
          #pragma unroll
          for (int r=0;r<4;r++){
            int tt = mi*16 + quad*4 + r;
            xp[dirA*4096 + tt*128 + j] = acc[mi][nt][r] + bv;
          }
        }
    }
    __syncthreads();

    // ---- Phase B: recurrence, one barrier per step ----
    for (int s=0;s<32;s++){
      int tx = rev ? (31-s) : s;
      float g = xp[dir*4096 + tx*128 + jj];
      const uint4* h4 = (const uint4*)hsh[dir];
      float a0=0.f,a1=0.f,a2=0.f,a3=0.f;
      #pragma unroll
      for (int k=0;k<4;k++){
        uint4 hv = h4[k];
        unsigned u0=whh[4*k], u1=whh[4*k+1], u2=whh[4*k+2], u3=whh[4*k+3];
        a0 = fmaf(lo16(hv.x), lo16(u0), a0);
        a0 = fmaf(hi16(hv.x), hi16(u0), a0);
        a1 = fmaf(lo16(hv.y), lo16(u1), a1);
        a1 = fmaf(hi16(hv.y), hi16(u1), a1);
        a2 = fmaf(lo16(hv.z), lo16(u2), a2);
        a2 = fmaf(hi16(hv.z), hi16(u2), a2);
        a3 = fmaf(lo16(hv.w), lo16(u3), a3);
        a3 = fmaf(hi16(hv.w), hi16(u3), a3);
      }
      g += (a0+a1) + (a2+a3);
      float act = (quad == 2) ? tanhfast(g) : sigm(g);   // gate = quad
      float gi = __shfl(act, col, 64);
      float gf = __shfl(act, 16+col, 64);
      float gg = __shfl(act, 32+col, 64);
      float go = __shfl(act, 48+col, 64);
      if (quad == 0){
        float cn = gf*creg + gi*gg;
        float hn = go*tanhfast(cn);
        creg = cn;
        u16 hb = fb(hn);
        hsh[dir][unit] = hb;
        obuf[tx*64 + dir*32 + unit] = hb;
      }
      __syncthreads();
    }
    if (layer < 2){
      for (int i=t;i<32*64;i+=256){ int tt=i>>6, k=i&63; xb[tt*136+k]=obuf[i]; }
      __syncthreads();
    }
  }
  for (int i=t;i<32*64;i+=256) latent[i] = bf(obuf[i]);
}

// ---- decoder linear: y[t,r] = b[r] + sum_{k<64} latent[t,k]*W[r,k] -> bf16 ----
__global__ void dec_lin_k(const float* __restrict__ latent, const float* __restrict__ W,
                          const float* __restrict__ b, u16* __restrict__ y){
  int i = blockIdx.x*blockDim.x + threadIdx.x;
  if (i >= 32*5120) return;
  int r = i % 5120, t = i / 5120;
  const float4* x4 = (const float4*)(latent + t*64);
  const float4* w4 = (const float4*)(W + (size_t)r*64);
  float acc = b[r];
  #pragma unroll
  for (int k=0;k<16;k++){
    float4 xv=x4[k]; float4 wv=w4[k];
    acc += xv.x*wv.x+xv.y*wv.y+xv.z*wv.z+xv.w*wv.w;
  }
  y[i] = fb(acc);
}

// ---- final conv (OC=3, IC=32, no ELU) + actor residual -> f32 out ----
__global__ void final_k(const u16* __restrict__ x, const int* __restrict__ idx,
                        const float* __restrict__ W, const float* __restrict__ bias,
                        const float* __restrict__ actor, float* __restrict__ out){
  __shared__ float Wsm[3*288];
  __shared__ float bsm[3];
  int t = threadIdx.x;
  for (int i=t;i<864;i+=256) Wsm[i]=W[i];
  if (t<3) bsm[t]=bias[t];
  __syncthreads();
  int g = blockIdx.x*256 + t;
  if (g >= 32*5023) return;
  int v = g % 5023, b = g / 5023;
  const u16* xb = x + (size_t)b*5023*32;
  const int* vix = idx + v*9;
  float a0=bsm[0], a1=bsm[1], a2=bsm[2];
  for (int s=0;s<9;s++){
    const ushort4* xr = (const ushort4*)(xb + (size_t)vix[s]*32);
    #pragma unroll
    for (int k=0;k<8;k++){
      ushort4 xv = xr[k];
      float x0=bf(xv.x), x1=bf(xv.y), x2=bf(xv.z), x3=bf(xv.w);
      int kk = s*32 + k*4;
      a0 += x0*Wsm[kk] + x1*Wsm[kk+1] + x2*Wsm[kk+2] + x3*Wsm[kk+3];
      a1 += x0*Wsm[288+kk] + x1*Wsm[288+kk+1] + x2*Wsm[288+kk+2] + x3*Wsm[288+kk+3];
      a2 += x0*Wsm[576+kk] + x1*Wsm[576+kk+1] + x2*Wsm[576+kk+2] + x3*Wsm[576+kk+3];
    }
  }
  out[(size_t)g*3+0] = a0 + actor[v*3+0];
  out[(size_t)g*3+1] = a1 + actor[v*3+1];
  out[(size_t)g*3+2] = a2 + actor[v*3+2];
}

extern "C" void kernel_launch(void* const* d_in, const int* in_sizes, int n_in,
                              void* d_out, int out_size, void* d_ws, size_t ws_size,
                              hipStream_t stream){
  (void)in_sizes; (void)n_in; (void)out_size; (void)ws_size;

  const float* audio = (const float*)d_in[0];
  const float* actor = (const float*)d_in[2];
  const int* sp[4]   = {(const int*)d_in[3],(const int*)d_in[4],(const int*)d_in[5],(const int*)d_in[6]};
  const int* drows[4]; const int* dcols[4]; const float* dvals[4];
  for (int i=0;i<4;i++){ drows[i]=(const int*)d_in[7+3*i]; dcols[i]=(const int*)d_in[8+3*i]; dvals[i]=(const float*)d_in[9+3*i]; }
  const int* urows[4]; const int* ucols[4]; const float* uvals[4];
  for (int i=0;i<4;i++){ urows[i]=(const int*)d_in[19+3*i]; ucols[i]=(const int*)d_in[20+3*i]; uvals[i]=(const float*)d_in[21+3*i]; }
  const float* encW[4]={(const float*)d_in[31],(const float*)d_in[33],(const float*)d_in[35],(const float*)d_in[37]};
  const float* encB[4]={(const float*)d_in[32],(const float*)d_in[34],(const float*)d_in[36],(const float*)d_in[38]};
  const float* enc_lin_W=(const float*)d_in[39]; const float* enc_lin_b=(const float*)d_in[40];
  const float* dec_lin_W=(const float*)d_in[41]; const float* dec_lin_b=(const float*)d_in[42];
  const float* decW[5]={(const float*)d_in[43],(const float*)d_in[45],(const float*)d_in[47],(const float*)d_in[49],(const float*)d_in[51]};
  const float* decB[5]={(const float*)d_in[44],(const float*)d_in[46],(const float*)d_in[48],(const float*)d_in[50],(const float*)d_in[52]};
  const float* audW=(const float*)d_in[53]; const float* audB=(const float*)d_in[54];
  const float* l0_Wih=(const float*)d_in[55]; const float* l0_Whh=(const float*)d_in[56];
  const float* l0_bih=(const float*)d_in[57]; const float* l0_bhh=(const float*)d_in[58];
  const float* l12_Wih=(const float*)d_in[59]; const float* l12_Whh=(const float*)d_in[60];
  const float* l12_bih=(const float*)d_in[61]; const float* l12_bhh=(const float*)d_in[62];
  float* out = (float*)d_out;

  // ---- workspace layout (bytes) ----
  char* base = (char*)d_ws;
  u16* A  = (u16*)base;                          // 10,287,104 B
  u16* Bb = (u16*)(base + 10287104);             // 20,574,208 B
  int* curBase = (int*)(base + 30891520);        // 8341 ints
  int* lstBase = (int*)(base + 30924928);        // 533,824 ints -> ends 33,060,224
  u16* Wbf = (u16*)(base + 33060224);            // 1,363,968 bf16 = 2,727,936 B
  float* sm = (float*)(base + 35788160);
  float* h0     = sm;                 // 4096
  float* latent = sm + 4096;          // 2048

  // bf16 weight segments: enc1,enc2,enc3,dec0,dec1,dec2,dec3
  const int wsz[7] = {64*288, 128*576, 256*1152, 256*2304, 128*2304, 64*1152, 32*576};
  WCast WC; int wcum = 0;
  const float* wsrc[7] = {encW[1],encW[2],encW[3],decW[0],decW[1],decW[2],decW[3]};
  int wo[7];
  for (int k=0;k<7;k++){ WC.src[k]=wsrc[k]; WC.cum[k]=wcum; wo[k]=wcum; wcum+=wsz[k]; }
  WC.cum[7]=wcum;

  // pool bookkeeping: d0,d1,d2,d3,u0,u1,u2,u3
  const int pVout[8] = {1256,314,79,20,5023,1256,314,79};
  const int pNnz[8]  = {3768,942,237,60,15069,3768,942,237};
  Lists L; int curoff=0, lstoff=0, totnnz=0;
  const int* prow[8] = {drows[0],drows[1],drows[2],drows[3],urows[0],urows[1],urows[2],urows[3]};
  int curo[8], lsto[8];
  for (int k=0;k<8;k++){
    L.rows[k]=prow[k]; L.nnz[k]=pNnz[k];
    L.curoff[k]=curoff; L.lstoff[k]=lstoff;
    curo[k]=curoff; lsto[k]=lstoff;
    curoff += pVout[k]; lstoff += pVout[k]*POOL_CAP; totnnz += pNnz[k];
  }
  hipMemsetAsync(curBase, 0, (size_t)curoff*4, stream);

  // ---- fused setup: lists + weight cast + audio emb + conv3 ----
  int NF = CDIV(totnnz,256), NC = CDIV(wcum,256), NC3 = CDIV(5023*32,256);
  setup_k<<<NF+NC+32+NC3,256,0,stream>>>(L, totnnz, NF, curBase, lstBase,
                                         WC, wcum, NC, Wbf,
                                         audio, audW, audB, h0,
                                         actor, sp[0], encW[0], encB[0], A);

  // ---- encoder (B=1): convs with fused input pools ----
  // stage1: pool d0 (5023->1256, C=32) fused into conv IC=32 OC=64; A -> Bb
  conv_pool_mfma<32,64><<<dim3(CDIV(1256,64),1),256,0,stream>>>(
      A, sp[1], dcols[0], dvals[0], curBase+curo[0], lstBase+lsto[0],
      Wbf+wo[0], encB[1], Bb, 1256, 64, 1256);
  // stage2: pool d1 (1256->314, C=64) fused into conv IC=64 OC=128; Bb -> A
  conv_pool_mfma<64,64><<<dim3(CDIV(314,64),2),256,0,stream>>>(
      Bb, sp[2], dcols[1], dvals[1], curBase+curo[1], lstBase+lsto[1],
      Wbf+wo[1], encB[2], A, 314, 128, 314);
  // stage3: pool d2 (314->79, C=128) fused into conv IC=128 OC=256; A -> Bb
  conv_pool_mfma<128,64><<<dim3(CDIV(79,64),4),256,0,stream>>>(
      A, sp[3], dcols[2], dvals[2], curBase+curo[2], lstBase+lsto[2],
      Wbf+wo[2], encB[3], Bb, 79, 256, 79);
  // pool d3 (79->20, C=256): tiny, separate; Bb -> A
  pool_g8_k<<<CDIV(20*32,256),256,0,stream>>>(Bb, dcols[3], dvals[3], curBase+curo[3], lstBase+lsto[3], A, 1, 79, 20, 256);

  enc_lin_k<<<64,256,0,stream>>>(A, enc_lin_W, enc_lin_b, h0);

  // ---- LSTM v4 (single block) ----
  lstm3_k<<<1,256,0,stream>>>(h0, l0_Wih, l0_Whh, l0_bih, l0_bhh,
                              l12_Wih, l12_Whh, l12_bih, l12_bhh, latent);

  // ---- decoder (B=32) ----
  dec_lin_k<<<CDIV(32*5120,256),256,0,stream>>>(latent, dec_lin_W, dec_lin_b, A); // (32,20,256)

  // j=3
  pool_g8_k<<<CDIV(32*79*32,256),256,0,stream>>>(A, ucols[3], uvals[3], curBase+curo[7], lstBase+lsto[7], Bb, 32, 20, 79, 256);
  conv_mfma<256,64,64><<<dim3(CDIV(2528,64),4),256,0,stream>>>(Bb, sp[3], Wbf+wo[3], decB[0], A, 79, 256, 2528);

  // j=2
  pool_g8_k<<<CDIV(32*314*32,256),256,0,stream>>>(A, ucols[2], uvals[2], curBase+curo[6], lstBase+lsto[6], Bb, 32, 79, 314, 256);
  conv_mfma<256,64,64><<<dim3(CDIV(10048,64),2),256,0,stream>>>(Bb, sp[2], Wbf+wo[4], decB[1], A, 314, 128, 10048);

  // j=1
  pool_g8_k<<<CDIV(32*1256*16,256),256,0,stream>>>(A, ucols[1], uvals[1], curBase+curo[5], lstBase+lsto[5], Bb, 32, 314, 1256, 128);
  conv_mfma<128,64,128><<<dim3(CDIV(40192,128),1),256,0,stream>>>(Bb, sp[1], Wbf+wo[5], decB[2], A, 1256, 64, 40192);

  // j=0
  pool_g8_k<<<CDIV(32*5023*8,256),256,0,stream>>>(A, ucols[0], uvals[0], curBase+curo[4], lstBase+lsto[4], Bb, 32, 1256, 5023, 64);
  conv_mfma<64,32,128><<<dim3(CDIV(160736,128),1),256,0,stream>>>(Bb, sp[0], Wbf+wo[6], decB[3], A, 5023, 32, 160736);

  // final conv (288->3) + actor residual -> f32 out
  final_k<<<CDIV(32*5023,256),256,0,stream>>>(A, sp[0], decW[4], decB[4], actor, out);
}

// Round 14
// 570.515 us; speedup vs baseline: 1.3257x; 1.3257x over previous
//
#include <hip/hip_runtime.h>
#include <cstdint>
#include <cstddef>

// SpiralAutoencoder forward, MI355X gfx950.
// Inputs f32, indices i32, output f32. Internal activations bf16, fp32 accum.
// Spiral convs = MFMA bf16 GEMM, software-pipelined K-loop (R9).
// LSTM v4 (measured optimum 63us: xproj via MFMA, 1 barrier/step, h bf16 LDS).
// Pools SEPARATE (R13 postmortem: fusing pool into conv A-fetch re-did the
//   gather per K-chunk on the critical path, 130us vs 10us — reverted).
// Pools 8ch/thread 16B loads; setup (lists+cast+audio+conv3) one dispatch.

typedef unsigned short u16;
typedef __attribute__((ext_vector_type(8))) short short8;
typedef __attribute__((ext_vector_type(4))) float float4v;
#define CDIV(a,b) (((a)+(b)-1)/(b))
#define POOL_CAP 64

__device__ __forceinline__ float bf(u16 u){ return __uint_as_float(((unsigned)u)<<16); }
__device__ __forceinline__ u16 fb(float x){
  unsigned u = __float_as_uint(x);
  unsigned r = u + 0x7fffu + ((u>>16)&1u);   // RNE
  return (u16)(r>>16);
}
__device__ __forceinline__ float lo16(unsigned u){ return __uint_as_float(u<<16); }
__device__ __forceinline__ float hi16(unsigned u){ return __uint_as_float(u & 0xffff0000u); }

struct WCast { const float* src[7]; int cum[8]; };
struct Lists {
  const int* rows[8];
  int nnz[8];
  int curoff[8];
  int lstoff[8];
};

// ---- fused setup: fill lists | cast weights | audio emb | conv3 ----
__global__ void __launch_bounds__(256) setup_k(
    Lists L, int totN, int NF, int* __restrict__ curBase, int* __restrict__ lstBase,
    WCast C, int totW, int NC, u16* __restrict__ Wbf,
    const float* __restrict__ audio, const float* __restrict__ audW,
    const float* __restrict__ audB, float* __restrict__ h0,
    const float* __restrict__ actor, const int* __restrict__ sp0,
    const float* __restrict__ encW0, const float* __restrict__ encB0,
    u16* __restrict__ outA){
  int blk = blockIdx.x;
  int tid = threadIdx.x;
  if (blk < NF){
    int i = blk*256 + tid;
    if (i < totN){
      int off = i, k = 0;
      while (off >= L.nnz[k]){ off -= L.nnz[k]; k++; }
      int r = L.rows[k][off];
      int p = atomicAdd(curBase + L.curoff[k] + r, 1);
      if (p < POOL_CAP) lstBase[L.lstoff[k] + r*POOL_CAP + p] = off;
    }
    return;
  }
  blk -= NF;
  if (blk < NC){
    int i = blk*256 + tid;
    if (i < totW){
      int k = 0;
      while (i >= C.cum[k+1]) k++;
      Wbf[i] = fb(C.src[k][i - C.cum[k]]);
    }
    return;
  }
  blk -= NC;
  if (blk < 32){
    int t = blk;
    int f = tid >> 2, sl = tid & 3;
    const float4* x4 = (const float4*)(audio + t*1536);
    const float4* w4 = (const float4*)(audW + f*1536);
    float acc = 0.f;
    for (int k=sl; k<384; k+=4){
      float4 xv = x4[k], wv = w4[k];
      acc += xv.x*wv.x + xv.y*wv.y + xv.z*wv.z + xv.w*wv.w;
    }
    acc += __shfl_down(acc, 2, 64);
    acc += __shfl_down(acc, 1, 64);
    if (sl == 0) h0[t*128 + f] = acc + audB[f];
    return;
  }
  blk -= 32;
  int i = blk*256 + tid;                     // conv3: IC=3 spiral conv
  if (i >= 5023*32) return;
  int o = i % 32; int v = i / 32;
  const float* wrow = encW0 + (size_t)o*27;
  const int* vix = sp0 + v*9;
  float acc = encB0[o];
  for (int s=0;s<9;s++){
    const float* xr = actor + (size_t)vix[s]*3;
    acc += xr[0]*wrow[s*3] + xr[1]*wrow[s*3+1] + xr[2]*wrow[s*3+2];
  }
  if (acc < 0.f) acc = expm1f(acc);
  outA[i] = fb(acc);
}

// ---- MFMA spiral conv, software-pipelined (R9) ----
template<int IC, int BN, int BM>
__global__ void __launch_bounds__(256) conv_mfma(
    const u16* __restrict__ x, const int* __restrict__ idx,
    const u16* __restrict__ Wb, const float* __restrict__ bias,
    u16* __restrict__ out, int V, int OC, int M){
  constexpr int K = 9*IC;
  constexpr int KC = K/32;
  constexpr int NT = BN/16;
  constexpr int MT = BM/64;
  constexpr int LOG2 = (IC==32?5: IC==64?6: IC==128?7:8);
  constexpr int AST = 40;
  __shared__ u16 Asm[2][BM*AST];
  __shared__ u16 Bsm[2][BN*AST];
  __shared__ int rowB[BM], rowV[BM];
  __shared__ int sidx[BM*9];
  int t = threadIdx.x;
  int m0 = blockIdx.x*BM;
  int o0 = blockIdx.y*BN;
  if (t < BM){
    int mg = m0 + t;
    if (mg < M){ int b = mg / V; rowB[t] = b; rowV[t] = mg - b*V; }
    else rowB[t] = -1;
  }
  __syncthreads();
  for (int i=t; i<BM*9; i+=256){
    int r = i/9, s = i - r*9;
    sidx[i] = (rowB[r] >= 0) ? idx[rowV[r]*9 + s] : 0;
  }
  int lane = t & 63, wave = t >> 6;
  int quad = lane >> 4, col = lane & 15;
  float4v acc[MT][NT];
  #pragma unroll
  for (int mi=0;mi<MT;mi++)
    #pragma unroll
    for (int nt=0;nt<NT;nt++) acc[mi][nt] = (float4v)0.f;

  uint4 aval[MT]; uint4 bval;
  auto fetch = [&](int kc){
    int s  = (kc*32) >> LOG2;
    int c0 = (kc*32) & (IC-1);
    #pragma unroll
    for (int rpt=0; rpt<MT; ++rpt){
      int seg = t + 256*rpt;
      int arow = seg >> 2, aq = seg & 3;
      int b = rowB[arow];
      uint4 v = {0u,0u,0u,0u};
      if (b >= 0){
        int ix = sidx[arow*9 + s];
        v = *(const uint4*)(x + ((size_t)b*V + ix)*IC + c0 + aq*8);
      }
      aval[rpt] = v;
    }
    if (t < BN*4){
      int br = t >> 2, bq = t & 3;
      bval = *(const uint4*)(Wb + (size_t)(o0+br)*K + kc*32 + bq*8);
    }
  };

  __syncthreads();
  fetch(0);

  for (int kc = 0; kc < KC; ++kc){
    int buf = kc & 1;
    #pragma unroll
    for (int rpt=0; rpt<MT; ++rpt){
      int seg = t + 256*rpt;
      int arow = seg >> 2, aq = seg & 3;
      *(uint4*)&Asm[buf][arow*AST + aq*8] = aval[rpt];
    }
    if (t < BN*4){
      int br = t >> 2, bq = t & 3;
      *(uint4*)&Bsm[buf][br*AST + bq*8] = bval;
    }
    __syncthreads();
    if (kc+1 < KC) fetch(kc+1);
    short8 a[MT];
    #pragma unroll
    for (int mi=0;mi<MT;mi++)
      a[mi] = *(const short8*)&Asm[buf][(wave*MT*16 + mi*16 + col)*AST + quad*8];
    #pragma unroll
    for (int nt=0; nt<NT; ++nt){
      short8 bfr = *(const short8*)&Bsm[buf][(nt*16 + col)*AST + quad*8];
      #pragma unroll
      for (int mi=0;mi<MT;mi++)
        acc[mi][nt] = __builtin_amdgcn_mfma_f32_16x16x32_bf16(a[mi], bfr, acc[mi][nt], 0, 0, 0);
    }
  }
  #pragma unroll
  for (int mi=0;mi<MT;mi++){
    #pragma unroll
    for (int nt=0; nt<NT; ++nt){
      int o = o0 + nt*16 + col;
      float bv = bias[o];
      #pragma unroll
      for (int r=0;r<4;r++){
        int mg = m0 + wave*MT*16 + mi*16 + quad*4 + r;
        if (mg < M){
          float val = acc[mi][nt][r] + bv;
          if (val < 0.f) val = expm1f(val);
          out[(size_t)mg*OC + o] = fb(val);
        }
      }
    }
  }
}

// ---- pool gather, 8 channels/thread (16B loads) ----
__global__ void pool_g8_k(const u16* __restrict__ x, const int* __restrict__ cols,
                          const float* __restrict__ vals, const int* __restrict__ cur,
                          const int* __restrict__ lst, u16* __restrict__ out,
                          int B, int Vin, int Vout, int C){
  int C8 = C >> 3;
  int total = B*Vout*C8;
  int i = blockIdx.x*blockDim.x + threadIdx.x;
  if (i >= total) return;
  int c8 = i % C8; int tt = i / C8; int r = tt % Vout; int b = tt / Vout;
  int deg = cur[r]; if (deg > POOL_CAP) deg = POOL_CAP;
  const int* le = lst + r*POOL_CAP;
  float a0=0.f,a1=0.f,a2=0.f,a3=0.f,a4=0.f,a5=0.f,a6=0.f,a7=0.f;
  for (int k=0;k<deg;k++){
    int e = le[k];
    float v = vals[e];
    uint4 xv = *(const uint4*)(x + ((size_t)b*Vin + (size_t)cols[e])*C + c8*8);
    a0 += v*lo16(xv.x); a1 += v*hi16(xv.x);
    a2 += v*lo16(xv.y); a3 += v*hi16(xv.y);
    a4 += v*lo16(xv.z); a5 += v*hi16(xv.z);
    a6 += v*lo16(xv.w); a7 += v*hi16(xv.w);
  }
  uint4 o;
  o.x = ((unsigned)fb(a0)) | (((unsigned)fb(a1))<<16);
  o.y = ((unsigned)fb(a2)) | (((unsigned)fb(a3))<<16);
  o.z = ((unsigned)fb(a4)) | (((unsigned)fb(a5))<<16);
  o.w = ((unsigned)fb(a6)) | (((unsigned)fb(a7))<<16);
  *(uint4*)(out + ((size_t)b*Vout + (size_t)r)*C + c8*8) = o;
}

// ---- encoder linear, split-K + broadcast into h0[:,64:] ----
__global__ void __launch_bounds__(256) enc_lin_k(
    const u16* __restrict__ x, const float* __restrict__ W,
    const float* __restrict__ b, float* __restrict__ h0){
  int f = blockIdx.x;
  int t = threadIdx.x;
  const ushort4* x4 = (const ushort4*)x;
  const float4* w4 = (const float4*)(W + (size_t)f*5120);
  float acc = 0.f;
  for (int k=t; k<1280; k+=256){
    ushort4 xv = x4[k]; float4 wv = w4[k];
    acc += bf(xv.x)*wv.x + bf(xv.y)*wv.y + bf(xv.z)*wv.z + bf(xv.w)*wv.w;
  }
  #pragma unroll
  for (int off=32; off; off>>=1) acc += __shfl_down(acc, off, 64);
  __shared__ float red[4];
  if ((t & 63) == 0) red[t>>6] = acc;
  __syncthreads();
  if (t < 32){
    float zf = b[f] + red[0] + red[1] + red[2] + red[3];
    h0[t*128 + 64 + f] = zf;
  }
}

// ---- LSTM v4 (measured optimum) ----
__device__ __forceinline__ float sigm(float x){ return 1.f/(1.f+__expf(-x)); }
__device__ __forceinline__ float tanhfast(float x){ return 1.f - 2.f/(__expf(2.f*x)+1.f); }

__global__ void __launch_bounds__(256) lstm3_k(
    const float* __restrict__ h0,
    const float* __restrict__ l0_Wih, const float* __restrict__ l0_Whh,
    const float* __restrict__ l0_bih, const float* __restrict__ l0_bhh,
    const float* __restrict__ l12_Wih, const float* __restrict__ l12_Whh,
    const float* __restrict__ l12_bih, const float* __restrict__ l12_bhh,
    float* __restrict__ latent){
  __shared__ __align__(16) u16 xb[32*136];       // x, bf16, stride 136
  __shared__ __align__(16) float xp[2*32*128];   // xproj+bias, [dir][t][j]
  __shared__ __align__(16) u16 obuf[32*64];
  __shared__ __align__(16) u16 hsh[2][32];
  __shared__ float bias_l[256];
  int t = threadIdx.x;
  int lane = t & 63, wave = t >> 6;
  int quad = lane >> 4, col = lane & 15;
  int dir = t >> 7;                 // recurrence: waves 0,1 -> dir0; 2,3 -> dir1
  bool rev = (dir == 1);
  int w2 = (t >> 6) & 1;            // which wave within dir
  int unit = w2*16 + col;           // hidden unit 0..31
  int jj = quad*32 + unit;          // Wih/Whh row (gate*32+unit)

  for (int i=t;i<32*128;i+=256){ int tt=i>>7, k=i&127; xb[tt*136+k]=fb(h0[i]); }

  for (int layer=0; layer<3; layer++){
    int IN = (layer==0)?128:64;
    const float *Wih,*Whh,*bih,*bhh;
    if (layer==0){ Wih=l0_Wih; Whh=l0_Whh; bih=l0_bih; bhh=l0_bhh; }
    else {
      int mb=(layer-1)*2;
      Wih=l12_Wih + (size_t)mb*128*64; Whh=l12_Whh + (size_t)mb*128*32;
      bih=l12_bih + mb*128; bhh=l12_bhh + mb*128;
    }
    const float* WhhD = Whh + (size_t)dir*128*32 + (size_t)jj*32;
    unsigned whh[16];
    #pragma unroll
    for (int k=0;k<16;k++){
      float2 w = *(const float2*)&WhhD[2*k];
      whh[k] = ((unsigned)fb(w.x)) | (((unsigned)fb(w.y))<<16);
    }
    bias_l[t] = bih[dir*128 + (t&127)] + bhh[dir*128 + (t&127)];
    if (quad == 0) hsh[dir][unit] = 0;
    float creg = 0.f;                // c for this lane's unit (quad==0 lanes)
    __syncthreads();

    // ---- Phase A: xproj[dirA][t][j] = x @ WihA^T + bias, via MFMA ----
    {
      int dirA = wave >> 1, o0 = (wave & 1)*64;
      const float* WA = Wih + (size_t)dirA*128*IN;
      float4v acc[2][4];
      #pragma unroll
      for (int mi=0;mi<2;mi++)
        #pragma unroll
        for (int nt=0;nt<4;nt++) acc[mi][nt] = (float4v)0.f;
      for (int kc=0; kc<IN/32; ++kc){
        short8 bfrag[4];
        #pragma unroll
        for (int nt=0;nt<4;nt++){
          const float* src = WA + (size_t)(o0+nt*16+col)*IN + kc*32 + quad*8;
          float4 w0 = *(const float4*)src;
          float4 w1 = *(const float4*)(src+4);
          alignas(16) u16 tmp[8] = {fb(w0.x),fb(w0.y),fb(w0.z),fb(w0.w),
                                    fb(w1.x),fb(w1.y),fb(w1.z),fb(w1.w)};
          bfrag[nt] = *(const short8*)tmp;
        }
        short8 afrag[2];
        #pragma unroll
        for (int mi=0;mi<2;mi++)
          afrag[mi] = *(const short8*)&xb[(mi*16+col)*136 + kc*32 + quad*8];
        #pragma unroll
        for (int nt=0;nt<4;nt++)
          #pragma unroll
          for (int mi=0;mi<2;mi++)
            acc[mi][nt] = __builtin_amdgcn_mfma_f32_16x16x32_bf16(afrag[mi], bfrag[nt], acc[mi][nt], 0, 0, 0);
      }
      #pragma unroll
      for (int mi=0;mi<2;mi++)
        #pragma unroll
        for (int nt=0;nt<4;nt++){
          int j = o0 + nt*16 + col;
          float bv = bias_l[dirA*128 + j];
          #pragma unroll
          for (int r=0;r<4;r++){
            int tt = mi*16 + quad*4 + r;
            xp[dirA*4096 + tt*128 + j] = acc[mi][nt][r] + bv;
          }
        }
    }
    __syncthreads();

    // ---- Phase B: recurrence, one barrier per step ----
    for (int s=0;s<32;s++){
      int tx = rev ? (31-s) : s;
      float g = xp[dir*4096 + tx*128 + jj];
      const uint4* h4 = (const uint4*)hsh[dir];
      float a0=0.f,a1=0.f,a2=0.f,a3=0.f;
      #pragma unroll
      for (int k=0;k<4;k++){
        uint4 hv = h4[k];
        unsigned u0=whh[4*k], u1=whh[4*k+1], u2=whh[4*k+2], u3=whh[4*k+3];
        a0 = fmaf(lo16(hv.x), lo16(u0), a0);
        a0 = fmaf(hi16(hv.x), hi16(u0), a0);
        a1 = fmaf(lo16(hv.y), lo16(u1), a1);
        a1 = fmaf(hi16(hv.y), hi16(u1), a1);
        a2 = fmaf(lo16(hv.z), lo16(u2), a2);
        a2 = fmaf(hi16(hv.z), hi16(u2), a2);
        a3 = fmaf(lo16(hv.w), lo16(u3), a3);
        a3 = fmaf(hi16(hv.w), hi16(u3), a3);
      }
      g += (a0+a1) + (a2+a3);
      float act = (quad == 2) ? tanhfast(g) : sigm(g);   // gate = quad
      float gi = __shfl(act, col, 64);
      float gf = __shfl(act, 16+col, 64);
      float gg = __shfl(act, 32+col, 64);
      float go = __shfl(act, 48+col, 64);
      if (quad == 0){
        float cn = gf*creg + gi*gg;
        float hn = go*tanhfast(cn);
        creg = cn;
        u16 hb = fb(hn);
        hsh[dir][unit] = hb;
        obuf[tx*64 + dir*32 + unit] = hb;
      }
      __syncthreads();
    }
    if (layer < 2){
      for (int i=t;i<32*64;i+=256){ int tt=i>>6, k=i&63; xb[tt*136+k]=obuf[i]; }
      __syncthreads();
    }
  }
  for (int i=t;i<32*64;i+=256) latent[i] = bf(obuf[i]);
}

// ---- decoder linear: y[t,r] = b[r] + sum_{k<64} latent[t,k]*W[r,k] -> bf16 ----
__global__ void dec_lin_k(const float* __restrict__ latent, const float* __restrict__ W,
                          const float* __restrict__ b, u16* __restrict__ y){
  int i = blockIdx.x*blockDim.x + threadIdx.x;
  if (i >= 32*5120) return;
  int r = i % 5120, t = i / 5120;
  const float4* x4 = (const float4*)(latent + t*64);
  const float4* w4 = (const float4*)(W + (size_t)r*64);
  float acc = b[r];
  #pragma unroll
  for (int k=0;k<16;k++){
    float4 xv=x4[k]; float4 wv=w4[k];
    acc += xv.x*wv.x+xv.y*wv.y+xv.z*wv.z+xv.w*wv.w;
  }
  y[i] = fb(acc);
}

// ---- final conv (OC=3, IC=32, no ELU) + actor residual -> f32 out ----
__global__ void final_k(const u16* __restrict__ x, const int* __restrict__ idx,
                        const float* __restrict__ W, const float* __restrict__ bias,
                        const float* __restrict__ actor, float* __restrict__ out){
  __shared__ float Wsm[3*288];
  __shared__ float bsm[3];
  int t = threadIdx.x;
  for (int i=t;i<864;i+=256) Wsm[i]=W[i];
  if (t<3) bsm[t]=bias[t];
  __syncthreads();
  int g = blockIdx.x*256 + t;
  if (g >= 32*5023) return;
  int v = g % 5023, b = g / 5023;
  const u16* xb = x + (size_t)b*5023*32;
  const int* vix = idx + v*9;
  float a0=bsm[0], a1=bsm[1], a2=bsm[2];
  for (int s=0;s<9;s++){
    const ushort4* xr = (const ushort4*)(xb + (size_t)vix[s]*32);
    #pragma unroll
    for (int k=0;k<8;k++){
      ushort4 xv = xr[k];
      float x0=bf(xv.x), x1=bf(xv.y), x2=bf(xv.z), x3=bf(xv.w);
      int kk = s*32 + k*4;
      a0 += x0*Wsm[kk] + x1*Wsm[kk+1] + x2*Wsm[kk+2] + x3*Wsm[kk+3];
      a1 += x0*Wsm[288+kk] + x1*Wsm[288+kk+1] + x2*Wsm[288+kk+2] + x3*Wsm[288+kk+3];
      a2 += x0*Wsm[576+kk] + x1*Wsm[576+kk+1] + x2*Wsm[576+kk+2] + x3*Wsm[576+kk+3];
    }
  }
  out[(size_t)g*3+0] = a0 + actor[v*3+0];
  out[(size_t)g*3+1] = a1 + actor[v*3+1];
  out[(size_t)g*3+2] = a2 + actor[v*3+2];
}

extern "C" void kernel_launch(void* const* d_in, const int* in_sizes, int n_in,
                              void* d_out, int out_size, void* d_ws, size_t ws_size,
                              hipStream_t stream){
  (void)in_sizes; (void)n_in; (void)out_size; (void)ws_size;

  const float* audio = (const float*)d_in[0];
  const float* actor = (const float*)d_in[2];
  const int* sp[4]   = {(const int*)d_in[3],(const int*)d_in[4],(const int*)d_in[5],(const int*)d_in[6]};
  const int* drows[4]; const int* dcols[4]; const float* dvals[4];
  for (int i=0;i<4;i++){ drows[i]=(const int*)d_in[7+3*i]; dcols[i]=(const int*)d_in[8+3*i]; dvals[i]=(const float*)d_in[9+3*i]; }
  const int* urows[4]; const int* ucols[4]; const float* uvals[4];
  for (int i=0;i<4;i++){ urows[i]=(const int*)d_in[19+3*i]; ucols[i]=(const int*)d_in[20+3*i]; uvals[i]=(const float*)d_in[21+3*i]; }
  const float* encW[4]={(const float*)d_in[31],(const float*)d_in[33],(const float*)d_in[35],(const float*)d_in[37]};
  const float* encB[4]={(const float*)d_in[32],(const float*)d_in[34],(const float*)d_in[36],(const float*)d_in[38]};
  const float* enc_lin_W=(const float*)d_in[39]; const float* enc_lin_b=(const float*)d_in[40];
  const float* dec_lin_W=(const float*)d_in[41]; const float* dec_lin_b=(const float*)d_in[42];
  const float* decW[5]={(const float*)d_in[43],(const float*)d_in[45],(const float*)d_in[47],(const float*)d_in[49],(const float*)d_in[51]};
  const float* decB[5]={(const float*)d_in[44],(const float*)d_in[46],(const float*)d_in[48],(const float*)d_in[50],(const float*)d_in[52]};
  const float* audW=(const float*)d_in[53]; const float* audB=(const float*)d_in[54];
  const float* l0_Wih=(const float*)d_in[55]; const float* l0_Whh=(const float*)d_in[56];
  const float* l0_bih=(const float*)d_in[57]; const float* l0_bhh=(const float*)d_in[58];
  const float* l12_Wih=(const float*)d_in[59]; const float* l12_Whh=(const float*)d_in[60];
  const float* l12_bih=(const float*)d_in[61]; const float* l12_bhh=(const float*)d_in[62];
  float* out = (float*)d_out;

  // ---- workspace layout (bytes) ----
  char* base = (char*)d_ws;
  u16* A  = (u16*)base;                          // 10,287,104 B
  u16* Bb = (u16*)(base + 10287104);             // 20,574,208 B
  int* curBase = (int*)(base + 30891520);        // 8341 ints
  int* lstBase = (int*)(base + 30924928);        // 533,824 ints -> ends 33,060,224
  u16* Wbf = (u16*)(base + 33060224);            // 1,363,968 bf16 = 2,727,936 B
  float* sm = (float*)(base + 35788160);
  float* h0     = sm;                 // 4096
  float* latent = sm + 4096;          // 2048

  // bf16 weight segments: enc1,enc2,enc3,dec0,dec1,dec2,dec3
  const int wsz[7] = {64*288, 128*576, 256*1152, 256*2304, 128*2304, 64*1152, 32*576};
  WCast WC; int wcum = 0;
  const float* wsrc[7] = {encW[1],encW[2],encW[3],decW[0],decW[1],decW[2],decW[3]};
  int wo[7];
  for (int k=0;k<7;k++){ WC.src[k]=wsrc[k]; WC.cum[k]=wcum; wo[k]=wcum; wcum+=wsz[k]; }
  WC.cum[7]=wcum;

  // pool bookkeeping: d0,d1,d2,d3,u0,u1,u2,u3
  const int pVout[8] = {1256,314,79,20,5023,1256,314,79};
  const int pNnz[8]  = {3768,942,237,60,15069,3768,942,237};
  Lists L; int curoff=0, lstoff=0, totnnz=0;
  const int* prow[8] = {drows[0],drows[1],drows[2],drows[3],urows[0],urows[1],urows[2],urows[3]};
  int curo[8], lsto[8];
  for (int k=0;k<8;k++){
    L.rows[k]=prow[k]; L.nnz[k]=pNnz[k];
    L.curoff[k]=curoff; L.lstoff[k]=lstoff;
    curo[k]=curoff; lsto[k]=lstoff;
    curoff += pVout[k]; lstoff += pVout[k]*POOL_CAP; totnnz += pNnz[k];
  }
  hipMemsetAsync(curBase, 0, (size_t)curoff*4, stream);

  // ---- fused setup: lists + weight cast + audio emb + conv3 ----
  int NF = CDIV(totnnz,256), NC = CDIV(wcum,256), NC3 = CDIV(5023*32,256);
  setup_k<<<NF+NC+32+NC3,256,0,stream>>>(L, totnnz, NF, curBase, lstBase,
                                         WC, wcum, NC, Wbf,
                                         audio, audW, audB, h0,
                                         actor, sp[0], encW[0], encB[0], A);

  // ---- encoder (B=1): separate pools + pipelined convs ----
  pool_g8_k<<<CDIV(1256*4,256),256,0,stream>>>(A, dcols[0], dvals[0], curBase+curo[0], lstBase+lsto[0], Bb, 1, 5023, 1256, 32);
  conv_mfma<32,64,64><<<dim3(CDIV(1256,64),1),256,0,stream>>>(Bb, sp[1], Wbf+wo[0], encB[1], A, 1256, 64, 1256);
  pool_g8_k<<<CDIV(314*8,256),256,0,stream>>>(A, dcols[1], dvals[1], curBase+curo[1], lstBase+lsto[1], Bb, 1, 1256, 314, 64);
  conv_mfma<64,64,64><<<dim3(CDIV(314,64),2),256,0,stream>>>(Bb, sp[2], Wbf+wo[1], encB[2], A, 314, 128, 314);
  pool_g8_k<<<CDIV(79*16,256),256,0,stream>>>(A, dcols[2], dvals[2], curBase+curo[2], lstBase+lsto[2], Bb, 1, 314, 79, 128);
  conv_mfma<128,64,64><<<dim3(CDIV(79,64),4),256,0,stream>>>(Bb, sp[3], Wbf+wo[2], encB[3], A, 79, 256, 79);
  pool_g8_k<<<CDIV(20*32,256),256,0,stream>>>(A, dcols[3], dvals[3], curBase+curo[3], lstBase+lsto[3], Bb, 1, 79, 20, 256);

  enc_lin_k<<<64,256,0,stream>>>(Bb, enc_lin_W, enc_lin_b, h0);

  // ---- LSTM v4 (single block) ----
  lstm3_k<<<1,256,0,stream>>>(h0, l0_Wih, l0_Whh, l0_bih, l0_bhh,
                              l12_Wih, l12_Whh, l12_bih, l12_bhh, latent);

  // ---- decoder (B=32) ----
  dec_lin_k<<<CDIV(32*5120,256),256,0,stream>>>(latent, dec_lin_W, dec_lin_b, A); // (32,20,256)

  // j=3
  pool_g8_k<<<CDIV(32*79*32,256),256,0,stream>>>(A, ucols[3], uvals[3], curBase+curo[7], lstBase+lsto[7], Bb, 32, 20, 79, 256);
  conv_mfma<256,64,64><<<dim3(CDIV(2528,64),4),256,0,stream>>>(Bb, sp[3], Wbf+wo[3], decB[0], A, 79, 256, 2528);

  // j=2
  pool_g8_k<<<CDIV(32*314*32,256),256,0,stream>>>(A, ucols[2], uvals[2], curBase+curo[6], lstBase+lsto[6], Bb, 32, 79, 314, 256);
  conv_mfma<256,64,64><<<dim3(CDIV(10048,64),2),256,0,stream>>>(Bb, sp[2], Wbf+wo[4], decB[1], A, 314, 128, 10048);

  // j=1
  pool_g8_k<<<CDIV(32*1256*16,256),256,0,stream>>>(A, ucols[1], uvals[1], curBase+curo[5], lstBase+lsto[5], Bb, 32, 314, 1256, 128);
  conv_mfma<128,64,128><<<dim3(CDIV(40192,128),1),256,0,stream>>>(Bb, sp[1], Wbf+wo[5], decB[2], A, 1256, 64, 40192);

  // j=0
  pool_g8_k<<<CDIV(32*5023*8,256),256,0,stream>>>(A, ucols[0], uvals[0], curBase+curo[4], lstBase+lsto[4], Bb, 32, 1256, 5023, 64);
  conv_mfma<64,32,128><<<dim3(CDIV(160736,128),1),256,0,stream>>>(Bb, sp[0], Wbf+wo[6], decB[3], A, 5023, 32, 160736);

  // final conv (288->3) + actor residual -> f32 out
  final_k<<<CDIV(32*5023,256),256,0,stream>>>(A, sp[0], decW[4], decB[4], actor, out);
}